// Round 5
// baseline (315.182 us; speedup 1.0000x reference)
//
#include <hip/hip_runtime.h>
#include <math.h>

#define BB  2
#define SS  2048
#define DD  768
#define HH  12
#define HDD 64
#define BSR (BB * SS)   // 4096

typedef __attribute__((ext_vector_type(8))) short bf16x8;   // 8 bf16 = 4 VGPRs
typedef __attribute__((ext_vector_type(4))) float f32x4;
typedef __attribute__((ext_vector_type(4))) int  i32x4;     // 16B copy unit

__device__ inline f32x4 mfma16(bf16x8 a, bf16x8 b, f32x4 c) {
    return __builtin_amdgcn_mfma_f32_16x16x32_bf16(a, b, c, 0, 0, 0);
}

// fp32 -> bf16 round-to-nearest-even
__device__ inline unsigned short f2b(float f) {
    unsigned int u = __float_as_uint(f);
    u += 0x7FFFu + ((u >> 16) & 1u);
    return (unsigned short)(u >> 16);
}

// async global->LDS 16B copy (LDS dest = wave-uniform base + lane*16; our
// chunk indexing keeps LDS offsets lane-contiguous)
__device__ inline void async_copy16(void* lds, const void* g) {
    __builtin_amdgcn_global_load_lds(
        (const __attribute__((address_space(1))) unsigned int*)g,
        (__attribute__((address_space(3))) unsigned int*)lds, 16, 0, 0);
}

// ---------------------------------------------------------------------------
// Conversion kernels
// ---------------------------------------------------------------------------
__global__ __launch_bounds__(256) void conv_x_kernel(
    const float* __restrict__ x, unsigned short* __restrict__ xb)
{
    int id = blockIdx.x * 256 + threadIdx.x;
    size_t base = (size_t)id * 8;
    float4 a = *(const float4*)&x[base];
    float4 b = *(const float4*)&x[base + 4];
    unsigned short o[8] = {f2b(a.x), f2b(a.y), f2b(a.z), f2b(a.w),
                           f2b(b.x), f2b(b.y), f2b(b.z), f2b(b.w)};
    *(i32x4*)&xb[base] = *(const i32x4*)o;
}

__global__ __launch_bounds__(256) void conv_wT_kernel(
    const float* __restrict__ w0, const float* __restrict__ w1,
    const float* __restrict__ w2, const float* __restrict__ w3,
    unsigned short* __restrict__ o0, unsigned short* __restrict__ o1,
    unsigned short* __restrict__ o2, unsigned short* __restrict__ o3)
{
    const float* w = (blockIdx.z == 0) ? w0 : (blockIdx.z == 1) ? w1
                   : (blockIdx.z == 2) ? w2 : w3;
    unsigned short* o = (blockIdx.z == 0) ? o0 : (blockIdx.z == 1) ? o1
                      : (blockIdx.z == 2) ? o2 : o3;
    const int n0 = blockIdx.x * 64;
    const int k0 = blockIdx.y * 64;
    const int tid = threadIdx.x;

    __shared__ unsigned short tile[64][72];

#pragma unroll
    for (int p = 0; p < 4; ++p) {
        int c  = p * 256 + tid;
        int kr = c >> 4;
        int nc = (c & 15) * 4;
        float4 v = *(const float4*)&w[(size_t)(k0 + kr) * DD + n0 + nc];
        tile[nc + 0][kr] = f2b(v.x);
        tile[nc + 1][kr] = f2b(v.y);
        tile[nc + 2][kr] = f2b(v.z);
        tile[nc + 3][kr] = f2b(v.w);
    }
    __syncthreads();
#pragma unroll
    for (int p = 0; p < 2; ++p) {
        int c  = p * 256 + tid;
        int nr = c >> 3;
        int kc = (c & 7) * 8;
        *(i32x4*)&o[(size_t)(n0 + nr) * DD + k0 + kc] = *(const i32x4*)&tile[nr][kc];
    }
}

// ---------------------------------------------------------------------------
// MFMA GEMM main loop, BK=64, XOR-swizzled LDS chunks (kills the 8-way
// bank conflict on b128 frag reads while keeping global_load_lds
// lane-contiguity: the swizzle is applied to the per-lane GLOBAL address).
// C[128x128] = A[128xK] * Bt[128xK]^T
// ---------------------------------------------------------------------------
__device__ inline void gemm_mainloop64(
    const unsigned short* __restrict__ A, const unsigned short* __restrict__ Bt,
    unsigned short (*As)[64], unsigned short (*Bs)[64],
    f32x4 acc[4][4], int m0, int n0, int tid, int mh, int nh, int l16, int quad)
{
    const int swz = l16 & 7;
    for (int k0 = 0; k0 < DD; k0 += 64) {
        __syncthreads();
#pragma unroll
        for (int p = 0; p < 4; ++p) {
            int c  = p * 256 + tid;
            int r  = c >> 3;
            int ch = (c & 7) ^ (r & 7);
            async_copy16(&As[r][(c & 7) * 8], &A[(size_t)(m0 + r) * DD + k0 + ch * 8]);
            async_copy16(&Bs[r][(c & 7) * 8], &Bt[(size_t)(n0 + r) * DD + k0 + ch * 8]);
        }
        __syncthreads();
        bf16x8 af0[4], af1[4], bf0[4], bf1[4];
#pragma unroll
        for (int mt = 0; mt < 4; ++mt) {
            int r = mh * 64 + mt * 16 + l16;
            af0[mt] = *(const bf16x8*)&As[r][((quad    ) ^ swz) * 8];
            af1[mt] = *(const bf16x8*)&As[r][((quad + 4) ^ swz) * 8];
        }
#pragma unroll
        for (int nt = 0; nt < 4; ++nt) {
            int r = nh * 64 + nt * 16 + l16;
            bf0[nt] = *(const bf16x8*)&Bs[r][((quad    ) ^ swz) * 8];
            bf1[nt] = *(const bf16x8*)&Bs[r][((quad + 4) ^ swz) * 8];
        }
#pragma unroll
        for (int mt = 0; mt < 4; ++mt)
#pragma unroll
            for (int nt = 0; nt < 4; ++nt) {
                acc[mt][nt] = mfma16(af0[mt], bf0[nt], acc[mt][nt]);
                acc[mt][nt] = mfma16(af1[mt], bf1[nt], acc[mt][nt]);
            }
    }
}

// ---------------------------------------------------------------------------
// QKV projection GEMM.  Q,K -> natural bf16 [bh][s][64]; V -> [bh][d][s].
// ---------------------------------------------------------------------------
__global__ __launch_bounds__(256) void qkv_gemm_kernel(
    const unsigned short* __restrict__ xb,
    const unsigned short* __restrict__ wqT, const unsigned short* __restrict__ wkT,
    const unsigned short* __restrict__ wvT,
    const float* __restrict__ bq, const float* __restrict__ bk,
    const float* __restrict__ bv,
    unsigned short* __restrict__ Qg, unsigned short* __restrict__ Kg,
    unsigned short* __restrict__ Vg)
{
    const int which = blockIdx.z;
    const unsigned short* Bt = (which == 0) ? wqT : (which == 1) ? wkT : wvT;
    const float* bias        = (which == 0) ? bq  : (which == 1) ? bk  : bv;
    unsigned short* out      = (which == 0) ? Qg  : (which == 1) ? Kg  : Vg;

    const int m0 = blockIdx.x * 128;
    const int n0 = blockIdx.y * 128;
    const int tid  = threadIdx.x;
    const int w    = tid >> 6;
    const int lane = tid & 63;
    const int quad = lane >> 4;
    const int l16  = lane & 15;
    const int mh   = w & 1;
    const int nh   = w >> 1;

    // union: staging (2 x 128x64 shorts = 32KB) vs epilogue T[64][136]
    __shared__ unsigned short smem[16384];
    unsigned short (*As)[64] = (unsigned short(*)[64])smem;
    unsigned short (*Bs)[64] = (unsigned short(*)[64])(smem + 8192);
    unsigned short (*T)[136] = (unsigned short(*)[136])smem;

    f32x4 zero = {0.f, 0.f, 0.f, 0.f};
    f32x4 acc[4][4];
#pragma unroll
    for (int i = 0; i < 4; ++i)
#pragma unroll
        for (int j = 0; j < 4; ++j) acc[i][j] = zero;

    gemm_mainloop64(xb, Bt, As, Bs, acc, m0, n0, tid, mh, nh, l16, quad);

    __syncthreads();   // staging reads done before T overwrite

    for (int pass = 0; pass < 2; ++pass) {
        if (pass) __syncthreads();
        if (which < 2) {
            // Q/K: T[s_local][d 0..127], pass = s-half (mh)
            if (mh == pass) {
#pragma unroll
                for (int nt = 0; nt < 4; ++nt) {
                    const int n = n0 + nh * 64 + nt * 16 + l16;
                    const float bvv = bias[n];
#pragma unroll
                    for (int mt = 0; mt < 4; ++mt)
#pragma unroll
                        for (int r = 0; r < 4; ++r)
                            T[mt * 16 + quad * 4 + r][nh * 64 + nt * 16 + l16] =
                                f2b(acc[mt][nt][r] + bvv);
                }
            }
            __syncthreads();
#pragma unroll
            for (int p2 = 0; p2 < 4; ++p2) {
                int c    = p2 * 256 + tid;
                int row  = c >> 4;
                int ck   = c & 15;
                int head = ck >> 3;
                int wi   = ck & 7;
                int sg   = m0 + pass * 64 + row;
                int bi   = sg >> 11, si = sg & 2047;
                int hcol = (n0 >> 6) + head;
                *(i32x4*)&out[(((size_t)(bi * HH + hcol)) * SS + si) * HDD + wi * 8] =
                    *(const i32x4*)&T[row][head * 64 + wi * 8];
            }
        } else {
            // V: T[d_local][s 0..127] (transpose), pass = head (nh)
            if (nh == pass) {
#pragma unroll
                for (int nt = 0; nt < 4; ++nt) {
                    const int n = n0 + pass * 64 + nt * 16 + l16;
                    const float bvv = bias[n];
#pragma unroll
                    for (int mt = 0; mt < 4; ++mt) {
                        ushort4 pk;
                        pk.x = f2b(acc[mt][nt][0] + bvv);
                        pk.y = f2b(acc[mt][nt][1] + bvv);
                        pk.z = f2b(acc[mt][nt][2] + bvv);
                        pk.w = f2b(acc[mt][nt][3] + bvv);
                        *(ushort4*)&T[nt * 16 + l16][mh * 64 + mt * 16 + quad * 4] = pk;
                    }
                }
            }
            __syncthreads();
            const int bi   = m0 >> 11;
            const int s0   = m0 & 2047;
            const int hcol = (n0 >> 6) + pass;
#pragma unroll
            for (int p2 = 0; p2 < 4; ++p2) {
                int c    = p2 * 256 + tid;
                int drow = c >> 4;
                int wi   = c & 15;
                *(i32x4*)&out[(((size_t)(bi * HH + hcol)) * HDD + drow) * SS + s0 + wi * 8] =
                    *(const i32x4*)&T[drow][wi * 8];
            }
        }
    }
}

// ---------------------------------------------------------------------------
// Output projection GEMM: 64x128 tile (384 blocks -> 1.5/CU), BK=64 swizzled.
// ctx(bf16) @ woT + bo -> fp32 out
// ---------------------------------------------------------------------------
__global__ __launch_bounds__(256) void out_gemm_kernel(
    const unsigned short* __restrict__ cb, const unsigned short* __restrict__ woT,
    const float* __restrict__ bo, float* __restrict__ out)
{
    const int m0 = blockIdx.x * 64;
    const int n0 = blockIdx.y * 128;
    const int tid  = threadIdx.x;
    const int w    = tid >> 6;
    const int lane = tid & 63;
    const int quad = lane >> 4;
    const int l16  = lane & 15;
    const int mh   = w & 1;     // 32-row half
    const int nh   = w >> 1;    // 64-col half
    const int swz  = l16 & 7;

    __shared__ unsigned short As[64][64];
    __shared__ unsigned short Bs[128][64];

    f32x4 zero = {0.f, 0.f, 0.f, 0.f};
    f32x4 acc[2][4];
#pragma unroll
    for (int i = 0; i < 2; ++i)
#pragma unroll
        for (int j = 0; j < 4; ++j) acc[i][j] = zero;

    for (int k0 = 0; k0 < DD; k0 += 64) {
        __syncthreads();
#pragma unroll
        for (int p = 0; p < 2; ++p) {         // A: 512 chunks
            int c  = p * 256 + tid;
            int r  = c >> 3;
            int ch = (c & 7) ^ (r & 7);
            async_copy16(&As[r][(c & 7) * 8], &cb[(size_t)(m0 + r) * DD + k0 + ch * 8]);
        }
#pragma unroll
        for (int p = 0; p < 4; ++p) {         // B: 1024 chunks
            int c  = p * 256 + tid;
            int r  = c >> 3;
            int ch = (c & 7) ^ (r & 7);
            async_copy16(&Bs[r][(c & 7) * 8], &woT[(size_t)(n0 + r) * DD + k0 + ch * 8]);
        }
        __syncthreads();
        bf16x8 af0[2], af1[2], bf0[4], bf1[4];
#pragma unroll
        for (int mt = 0; mt < 2; ++mt) {
            int r = mh * 32 + mt * 16 + l16;
            af0[mt] = *(const bf16x8*)&As[r][((quad    ) ^ swz) * 8];
            af1[mt] = *(const bf16x8*)&As[r][((quad + 4) ^ swz) * 8];
        }
#pragma unroll
        for (int nt = 0; nt < 4; ++nt) {
            int r = nh * 64 + nt * 16 + l16;
            bf0[nt] = *(const bf16x8*)&Bs[r][((quad    ) ^ swz) * 8];
            bf1[nt] = *(const bf16x8*)&Bs[r][((quad + 4) ^ swz) * 8];
        }
#pragma unroll
        for (int mt = 0; mt < 2; ++mt)
#pragma unroll
            for (int nt = 0; nt < 4; ++nt) {
                acc[mt][nt] = mfma16(af0[mt], bf0[nt], acc[mt][nt]);
                acc[mt][nt] = mfma16(af1[mt], bf1[nt], acc[mt][nt]);
            }
    }

#pragma unroll
    for (int nt = 0; nt < 4; ++nt) {
        const int n = n0 + nh * 64 + nt * 16 + l16;
        const float bvv = bo[n];
#pragma unroll
        for (int mt = 0; mt < 2; ++mt) {
            const int mbase = m0 + mh * 32 + mt * 16 + quad * 4;
#pragma unroll
            for (int r = 0; r < 4; ++r)
                out[(size_t)(mbase + r) * DD + n] = acc[mt][nt][r] + bvv;
        }
    }
}

// ---------------------------------------------------------------------------
// MFMA flash attention, transposed-S, BARRIER-FREE K-loop.
//   S^T = K·Q^T : A-frag = K rows read DIRECTLY from global (lane-addressable)
//   O^T = V^T·P^T : A-frag = V^T rows read directly from global [d][s]
// Only LDS use: per-wave P^T slab (wave-internal, lgkmcnt only, no barrier).
// ---------------------------------------------------------------------------
__global__ __launch_bounds__(256, 3) void attn_mfma_kernel(
    const unsigned short* __restrict__ Qg, const unsigned short* __restrict__ Kg,
    const unsigned short* __restrict__ Vg, unsigned short* __restrict__ ctx)
{
    const int qt = (SS / 64 - 1) - blockIdx.x;   // big tiles first
    const int h  = blockIdx.y;
    const int b  = blockIdx.z;
    const int tid  = threadIdx.x;
    const int w    = tid >> 6;
    const int lane = tid & 63;
    const int quad = lane >> 4;
    const int l16  = lane & 15;
    const int q0   = qt * 64;

    const size_t bh = (size_t)(b * HH + h);
    const unsigned short* qp = Qg + bh * SS * HDD;
    const unsigned short* kp = Kg + bh * SS * HDD;
    const unsigned short* vp = Vg + bh * HDD * SS;   // [d][s]

    __shared__ unsigned short PsT[4][16][72];        // per-wave slab [query][key/d]
    unsigned short* slab = &PsT[w][0][0];            // row stride 72

    // Q B-fragment in registers: B[k=d][n=query(l16)]
    const int query = q0 + w * 16 + l16;
    const bf16x8 qb0 = *(const bf16x8*)&qp[(size_t)query * HDD + quad * 8];
    const bf16x8 qb1 = *(const bf16x8*)&qp[(size_t)query * HDD + 32 + quad * 8];

    f32x4 zero = {0.f, 0.f, 0.f, 0.f};
    f32x4 o_acc[4];
    float m_i = -INFINITY, l_i = 0.f;
#pragma unroll
    for (int i = 0; i < 4; ++i) o_acc[i] = zero;

    // prefetch K fragments for tile 0 (A-layout: m=key=t*16+l16, k=quad*8+j)
    bf16x8 ka0[4], ka1[4];
#pragma unroll
    for (int t = 0; t < 4; ++t) {
        const size_t kr = (size_t)(t * 16 + l16) * HDD;
        ka0[t] = *(const bf16x8*)&kp[kr + quad * 8];
        ka1[t] = *(const bf16x8*)&kp[kr + 32 + quad * 8];
    }

    for (int kt = 0; kt <= qt; ++kt) {
        const int k0 = kt * 64;

        // V fragments for this tile, issued early (consumed after softmax)
        bf16x8 va0[4], va1[4];
#pragma unroll
        for (int t2 = 0; t2 < 4; ++t2) {
            const size_t vr = (size_t)(t2 * 16 + l16) * SS + k0;
            va0[t2] = *(const bf16x8*)&vp[vr + quad * 8];
            va1[t2] = *(const bf16x8*)&vp[vr + 32 + quad * 8];
        }

        // ---- S^T = K·Q^T ----
        f32x4 s_acc[4];
#pragma unroll
        for (int t = 0; t < 4; ++t) {
            s_acc[t] = mfma16(ka0[t], qb0, zero);
            s_acc[t] = mfma16(ka1[t], qb1, s_acc[t]);
        }

        // prefetch K for next tile (full iteration of latency to hide)
        if (kt < qt) {
            const int kn = k0 + 64;
#pragma unroll
            for (int t = 0; t < 4; ++t) {
                const size_t kr = (size_t)(kn + t * 16 + l16) * HDD;
                ka0[t] = *(const bf16x8*)&kp[kr + quad * 8];
                ka1[t] = *(const bf16x8*)&kp[kr + 32 + quad * 8];
            }
        }

        // ---- per-lane online softmax (lane owns one query) ----
        float ps[4][4];
        float mx = -INFINITY;
#pragma unroll
        for (int t = 0; t < 4; ++t)
#pragma unroll
            for (int r = 0; r < 4; ++r) {
                const int key = k0 + t * 16 + quad * 4 + r;
                float val = s_acc[t][r] * 0.125f;
                if (kt == qt && key > query) val = -INFINITY;
                ps[t][r] = val;
                mx = fmaxf(mx, val);
            }
        mx = fmaxf(mx, __shfl_xor(mx, 16));
        mx = fmaxf(mx, __shfl_xor(mx, 32));
        const float mnew  = fmaxf(m_i, mx);
        const float alpha = __expf(m_i - mnew);
        float lsum = 0.f;
#pragma unroll
        for (int t = 0; t < 4; ++t)
#pragma unroll
            for (int r = 0; r < 4; ++r) {
                float pv = __expf(ps[t][r] - mnew);
                ps[t][r] = pv;
                lsum += pv;
            }
        lsum += __shfl_xor(lsum, 16);
        lsum += __shfl_xor(lsum, 32);
        l_i = l_i * alpha + lsum;
        m_i = mnew;
#pragma unroll
        for (int t = 0; t < 4; ++t)
#pragma unroll
            for (int r = 0; r < 4; ++r) o_acc[t][r] *= alpha;

        // ---- P^T via per-wave slab (no barrier: wave-internal dep) ----
#pragma unroll
        for (int t = 0; t < 4; ++t) {
            ushort4 pk;
            pk.x = f2b(ps[t][0]);
            pk.y = f2b(ps[t][1]);
            pk.z = f2b(ps[t][2]);
            pk.w = f2b(ps[t][3]);
            *(ushort4*)&slab[l16 * 72 + t * 16 + quad * 4] = pk;
        }
        bf16x8 pb0 = *(const bf16x8*)&slab[l16 * 72 + quad * 8];
        bf16x8 pb1 = *(const bf16x8*)&slab[l16 * 72 + 32 + quad * 8];

        // ---- O^T += V^T · P^T ----
#pragma unroll
        for (int t2 = 0; t2 < 4; ++t2) {
            o_acc[t2] = mfma16(va0[t2], pb0, o_acc[t2]);
            o_acc[t2] = mfma16(va1[t2], pb1, o_acc[t2]);
        }
    }

    // ---- epilogue: normalize, bounce O^T -> [q][d] via own slab, store ----
    const float inv = 1.0f / l_i;
#pragma unroll
    for (int t2 = 0; t2 < 4; ++t2) {
        ushort4 pk;
        pk.x = f2b(o_acc[t2][0] * inv);
        pk.y = f2b(o_acc[t2][1] * inv);
        pk.z = f2b(o_acc[t2][2] * inv);
        pk.w = f2b(o_acc[t2][3] * inv);
        *(ushort4*)&slab[l16 * 72 + t2 * 16 + quad * 4] = pk;   // T[query][d]
    }
    // per-wave coalesced store of its 16 query rows (no block barrier needed)
#pragma unroll
    for (int p2 = 0; p2 < 2; ++p2) {
        int c   = p2 * 64 + lane;
        int row = c >> 3;      // 0..15
        int dc  = c & 7;
        *(i32x4*)&ctx[((size_t)(b * SS + q0 + w * 16 + row)) * DD + h * HDD + dc * 8] =
            *(const i32x4*)&slab[row * 72 + dc * 8];
    }
}

// ---------------------------------------------------------------------------
extern "C" void kernel_launch(void* const* d_in, const int* in_sizes, int n_in,
                              void* d_out, int out_size, void* d_ws, size_t ws_size,
                              hipStream_t stream)
{
    const float* x  = (const float*)d_in[0];
    const float* wq = (const float*)d_in[1];
    const float* bq = (const float*)d_in[2];
    const float* wk = (const float*)d_in[3];
    const float* bk = (const float*)d_in[4];
    const float* wv = (const float*)d_in[5];
    const float* bv = (const float*)d_in[6];
    const float* wo = (const float*)d_in[7];
    const float* bo = (const float*)d_in[8];
    float* out = (float*)d_out;

    char* p = (char*)d_ws;
    const size_t XB = (size_t)BSR * DD * 2;
    const size_t WB = (size_t)DD * DD * 2;
    unsigned short* xb  = (unsigned short*)p;            p += XB;
    unsigned short* wqT = (unsigned short*)p;            p += WB;
    unsigned short* wkT = (unsigned short*)p;            p += WB;
    unsigned short* wvT = (unsigned short*)p;            p += WB;
    unsigned short* woT = (unsigned short*)p;            p += WB;
    unsigned short* Qg  = (unsigned short*)p;            p += XB;
    unsigned short* Kg  = (unsigned short*)p;            p += XB;
    unsigned short* Vg  = (unsigned short*)p;            p += XB;
    unsigned short* cb  = (unsigned short*)p;            p += XB;

    conv_x_kernel<<<BSR * DD / (256 * 8), 256, 0, stream>>>(x, xb);
    conv_wT_kernel<<<dim3(DD / 64, DD / 64, 4), 256, 0, stream>>>(
        wq, wk, wv, wo, wqT, wkT, wvT, woT);
    qkv_gemm_kernel<<<dim3(BSR / 128, DD / 128, 3), 256, 0, stream>>>(
        xb, wqT, wkT, wvT, bq, bk, bv, Qg, Kg, Vg);
    attn_mfma_kernel<<<dim3(SS / 64, HH, BB), 256, 0, stream>>>(Qg, Kg, Vg, cb);
    out_gemm_kernel<<<dim3(BSR / 64, DD / 128), 256, 0, stream>>>(cb, woT, bo, out);
}

// Round 6
// 181.015 us; speedup vs baseline: 1.7412x; 1.7412x over previous
//
#include <hip/hip_runtime.h>
#include <math.h>

#define BB  2
#define SS  2048
#define DD  768
#define HH  12
#define HDD 64
#define BSR (BB * SS)   // 4096
#define NQT (SS / 64)   // 32 q-tiles

typedef __attribute__((ext_vector_type(8))) short bf16x8;   // 8 bf16 = 4 VGPRs
typedef __attribute__((ext_vector_type(4))) float f32x4;
typedef __attribute__((ext_vector_type(4))) int  i32x4;     // 16B copy unit

__device__ inline f32x4 mfma16(bf16x8 a, bf16x8 b, f32x4 c) {
    return __builtin_amdgcn_mfma_f32_16x16x32_bf16(a, b, c, 0, 0, 0);
}

// fp32 -> bf16 round-to-nearest-even
__device__ inline unsigned short f2b(float f) {
    unsigned int u = __float_as_uint(f);
    u += 0x7FFFu + ((u >> 16) & 1u);
    return (unsigned short)(u >> 16);
}
__device__ inline float b2f(unsigned short u) {
    return __uint_as_float((unsigned int)u << 16);
}

// async global->LDS 16B copy (LDS dest = wave-uniform base + lane*16)
__device__ inline void async_copy16(void* lds, const void* g) {
    __builtin_amdgcn_global_load_lds(
        (const __attribute__((address_space(1))) unsigned int*)g,
        (__attribute__((address_space(3))) unsigned int*)lds, 16, 0, 0);
}

// ---------------------------------------------------------------------------
// Conversion kernels
// ---------------------------------------------------------------------------
__global__ __launch_bounds__(256) void conv_x_kernel(
    const float* __restrict__ x, unsigned short* __restrict__ xb)
{
    int id = blockIdx.x * 256 + threadIdx.x;
    size_t base = (size_t)id * 8;
    float4 a = *(const float4*)&x[base];
    float4 b = *(const float4*)&x[base + 4];
    unsigned short o[8] = {f2b(a.x), f2b(a.y), f2b(a.z), f2b(a.w),
                           f2b(b.x), f2b(b.y), f2b(b.z), f2b(b.w)};
    *(i32x4*)&xb[base] = *(const i32x4*)o;
}

__global__ __launch_bounds__(256) void conv_wT_kernel(
    const float* __restrict__ w0, const float* __restrict__ w1,
    const float* __restrict__ w2, const float* __restrict__ w3,
    unsigned short* __restrict__ o0, unsigned short* __restrict__ o1,
    unsigned short* __restrict__ o2, unsigned short* __restrict__ o3)
{
    const float* w = (blockIdx.z == 0) ? w0 : (blockIdx.z == 1) ? w1
                   : (blockIdx.z == 2) ? w2 : w3;
    unsigned short* o = (blockIdx.z == 0) ? o0 : (blockIdx.z == 1) ? o1
                      : (blockIdx.z == 2) ? o2 : o3;
    const int n0 = blockIdx.x * 64;
    const int k0 = blockIdx.y * 64;
    const int tid = threadIdx.x;

    __shared__ unsigned short tile[64][72];

#pragma unroll
    for (int p = 0; p < 4; ++p) {
        int c  = p * 256 + tid;
        int kr = c >> 4;
        int nc = (c & 15) * 4;
        float4 v = *(const float4*)&w[(size_t)(k0 + kr) * DD + n0 + nc];
        tile[nc + 0][kr] = f2b(v.x);
        tile[nc + 1][kr] = f2b(v.y);
        tile[nc + 2][kr] = f2b(v.z);
        tile[nc + 3][kr] = f2b(v.w);
    }
    __syncthreads();
#pragma unroll
    for (int p = 0; p < 2; ++p) {
        int c  = p * 256 + tid;
        int nr = c >> 3;
        int kc = (c & 7) * 8;
        *(i32x4*)&o[(size_t)(n0 + nr) * DD + k0 + kc] = *(const i32x4*)&tile[nr][kc];
    }
}

// ---------------------------------------------------------------------------
// Shared MFMA mainloop: C[64x128] = A[64xK] * Bt[128xK]^T, BK=64, XOR-swizzled
// chunks (swizzle applied on the global-address side; de-swizzled on read).
// 4 waves: mh = 32-row half, nh = 64-col half; acc[2][4].
// ---------------------------------------------------------------------------
__device__ inline void mainloop_64x128(
    const unsigned short* __restrict__ A, const unsigned short* __restrict__ Bt,
    unsigned short (*As)[64], unsigned short (*Bs)[64],
    f32x4 acc[2][4], int m0, int n0, int tid, int mh, int nh, int l16, int quad)
{
    const int swz = l16 & 7;
    for (int k0 = 0; k0 < DD; k0 += 64) {
        __syncthreads();
#pragma unroll
        for (int p = 0; p < 2; ++p) {          // A: 512 chunks
            int c  = p * 256 + tid;
            int r  = c >> 3;
            int ch = (c & 7) ^ (r & 7);
            async_copy16(&As[r][(c & 7) * 8], &A[(size_t)(m0 + r) * DD + k0 + ch * 8]);
        }
#pragma unroll
        for (int p = 0; p < 4; ++p) {          // B: 1024 chunks
            int c  = p * 256 + tid;
            int r  = c >> 3;
            int ch = (c & 7) ^ (r & 7);
            async_copy16(&Bs[r][(c & 7) * 8], &Bt[(size_t)(n0 + r) * DD + k0 + ch * 8]);
        }
        __syncthreads();
        bf16x8 af0[2], af1[2], bf0[4], bf1[4];
#pragma unroll
        for (int mt = 0; mt < 2; ++mt) {
            int r = mh * 32 + mt * 16 + l16;
            af0[mt] = *(const bf16x8*)&As[r][((quad    ) ^ swz) * 8];
            af1[mt] = *(const bf16x8*)&As[r][((quad + 4) ^ swz) * 8];
        }
#pragma unroll
        for (int nt = 0; nt < 4; ++nt) {
            int r = nh * 64 + nt * 16 + l16;
            bf0[nt] = *(const bf16x8*)&Bs[r][((quad    ) ^ swz) * 8];
            bf1[nt] = *(const bf16x8*)&Bs[r][((quad + 4) ^ swz) * 8];
        }
#pragma unroll
        for (int mt = 0; mt < 2; ++mt)
#pragma unroll
            for (int nt = 0; nt < 4; ++nt) {
                acc[mt][nt] = mfma16(af0[mt], bf0[nt], acc[mt][nt]);
                acc[mt][nt] = mfma16(af1[mt], bf1[nt], acc[mt][nt]);
            }
    }
}

// ---------------------------------------------------------------------------
// QKV projection GEMM, 64x128 tile (1152 blocks).  Q,K -> bf16 [bh][s][64];
// V -> transposed bf16 [bh][d][s].  Epilogue re-layouts through LDS.
// ---------------------------------------------------------------------------
__global__ __launch_bounds__(256) void qkv_gemm_kernel(
    const unsigned short* __restrict__ xb,
    const unsigned short* __restrict__ wqT, const unsigned short* __restrict__ wkT,
    const unsigned short* __restrict__ wvT,
    const float* __restrict__ bq, const float* __restrict__ bk,
    const float* __restrict__ bv,
    unsigned short* __restrict__ Qg, unsigned short* __restrict__ Kg,
    unsigned short* __restrict__ Vg)
{
    const int which = blockIdx.z;
    const unsigned short* Bt = (which == 0) ? wqT : (which == 1) ? wkT : wvT;
    const float* bias        = (which == 0) ? bq  : (which == 1) ? bk  : bv;
    unsigned short* out      = (which == 0) ? Qg  : (which == 1) ? Kg  : Vg;

    const int m0 = blockIdx.x * 64;
    const int n0 = blockIdx.y * 128;
    const int tid  = threadIdx.x;
    const int w    = tid >> 6;
    const int lane = tid & 63;
    const int quad = lane >> 4;
    const int l16  = lane & 15;
    const int mh   = w & 1;
    const int nh   = w >> 1;

    // union: staging As[64][64]+Bs[128][64] (24 KiB) vs epilogue T[64][136]
    __shared__ unsigned short smem[12288];
    unsigned short (*As)[64]  = (unsigned short(*)[64])smem;
    unsigned short (*Bs)[64]  = (unsigned short(*)[64])(smem + 4096);
    unsigned short (*T)[136]  = (unsigned short(*)[136])smem;

    f32x4 zero = {0.f, 0.f, 0.f, 0.f};
    f32x4 acc[2][4];
#pragma unroll
    for (int i = 0; i < 2; ++i)
#pragma unroll
        for (int j = 0; j < 4; ++j) acc[i][j] = zero;

    mainloop_64x128(xb, Bt, As, Bs, acc, m0, n0, tid, mh, nh, l16, quad);

    __syncthreads();   // staging reads done before T overwrite

    if (which < 2) {
        // Q/K: fill T[row 0..63][col 0..127], one pass
#pragma unroll
        for (int nt = 0; nt < 4; ++nt) {
            const int col = nh * 64 + nt * 16 + l16;
            const float bvv = bias[n0 + col];
#pragma unroll
            for (int mt = 0; mt < 2; ++mt)
#pragma unroll
                for (int r = 0; r < 4; ++r)
                    T[mh * 32 + mt * 16 + quad * 4 + r][col] =
                        f2b(acc[mt][nt][r] + bvv);
        }
        __syncthreads();
#pragma unroll
        for (int p2 = 0; p2 < 4; ++p2) {
            int c    = p2 * 256 + tid;
            int row  = c >> 4;
            int ck   = c & 15;
            int head = ck >> 3;
            int wi   = ck & 7;
            int sg   = m0 + row;
            int bi   = sg >> 11, si = sg & 2047;
            int hcol = (n0 >> 6) + head;
            *(i32x4*)&out[(((size_t)(bi * HH + hcol)) * SS + si) * HDD + wi * 8] =
                *(const i32x4*)&T[row][head * 64 + wi * 8];
        }
    } else {
        // V: two passes over head; T[d 0..63][s 0..63]
        for (int pass = 0; pass < 2; ++pass) {
            if (pass) __syncthreads();
            if (nh == pass) {
#pragma unroll
                for (int nt = 0; nt < 4; ++nt) {
                    const float bvv = bias[n0 + pass * 64 + nt * 16 + l16];
#pragma unroll
                    for (int mt = 0; mt < 2; ++mt) {
                        ushort4 pk;
                        pk.x = f2b(acc[mt][nt][0] + bvv);
                        pk.y = f2b(acc[mt][nt][1] + bvv);
                        pk.z = f2b(acc[mt][nt][2] + bvv);
                        pk.w = f2b(acc[mt][nt][3] + bvv);
                        *(ushort4*)&T[nt * 16 + l16][mh * 32 + mt * 16 + quad * 4] = pk;
                    }
                }
            }
            __syncthreads();
            const int bi   = m0 >> 11;
            const int s0   = m0 & 2047;
            const int hcol = (n0 >> 6) + pass;
#pragma unroll
            for (int p2 = 0; p2 < 2; ++p2) {
                int c    = p2 * 256 + tid;
                int drow = c >> 3;
                int wi   = c & 7;
                *(i32x4*)&out[(((size_t)(bi * HH + hcol)) * HDD + drow) * SS + s0 + wi * 8] =
                    *(const i32x4*)&T[drow][wi * 8];
            }
        }
    }
}

// ---------------------------------------------------------------------------
// Output projection GEMM: 64x128 tile.  ctx(bf16) @ woT + bo -> fp32 out
// ---------------------------------------------------------------------------
__global__ __launch_bounds__(256) void out_gemm_kernel(
    const unsigned short* __restrict__ cb, const unsigned short* __restrict__ woT,
    const float* __restrict__ bo, float* __restrict__ out)
{
    const int m0 = blockIdx.x * 64;
    const int n0 = blockIdx.y * 128;
    const int tid  = threadIdx.x;
    const int w    = tid >> 6;
    const int lane = tid & 63;
    const int quad = lane >> 4;
    const int l16  = lane & 15;
    const int mh   = w & 1;
    const int nh   = w >> 1;

    __shared__ unsigned short As[64][64];
    __shared__ unsigned short Bs[128][64];

    f32x4 zero = {0.f, 0.f, 0.f, 0.f};
    f32x4 acc[2][4];
#pragma unroll
    for (int i = 0; i < 2; ++i)
#pragma unroll
        for (int j = 0; j < 4; ++j) acc[i][j] = zero;

    mainloop_64x128(cb, woT, As, Bs, acc, m0, n0, tid, mh, nh, l16, quad);

#pragma unroll
    for (int nt = 0; nt < 4; ++nt) {
        const int n = n0 + nh * 64 + nt * 16 + l16;
        const float bvv = bo[n];
#pragma unroll
        for (int mt = 0; mt < 2; ++mt) {
            const int mbase = m0 + mh * 32 + mt * 16 + quad * 4;
#pragma unroll
            for (int r = 0; r < 4; ++r)
                out[(size_t)(mbase + r) * DD + n] = acc[mt][nt][r] + bvv;
        }
    }
}

// ---------------------------------------------------------------------------
// MFMA flash attention, transposed-S, R4 LDS double-buffer structure,
// 2-way SPLIT-K over the causal K-range (flash-decoding).  Each split block
// writes unnormalized partials (O bf16, m/l fp32); merge_kernel combines.
// ---------------------------------------------------------------------------
__global__ __launch_bounds__(256, 3) void attn_mfma_kernel(
    const unsigned short* __restrict__ Qg, const unsigned short* __restrict__ Kg,
    const unsigned short* __restrict__ Vg, unsigned short* __restrict__ Opart,
    float* __restrict__ Mb, float* __restrict__ Lb)
{
    const int sp = blockIdx.x & 1;
    const int qt = (NQT - 1) - (blockIdx.x >> 1);   // big tiles first
    const int h  = blockIdx.y;
    const int b  = blockIdx.z;
    const int tid  = threadIdx.x;
    const int w    = tid >> 6;
    const int lane = tid & 63;
    const int quad = lane >> 4;
    const int l16  = lane & 15;
    const int q0   = qt * 64;

    const size_t bh = (size_t)(b * HH + h);
    const unsigned short* qp = Qg + bh * SS * HDD;
    const unsigned short* kp = Kg + bh * SS * HDD;
    const unsigned short* vp = Vg + bh * HDD * SS;   // [d][s]

    unsigned short* op = Opart + ((size_t)sp * BB * HH + bh) * SS * HDD;
    float* mp = Mb + ((size_t)sp * BB * HH + bh) * SS;
    float* lp = Lb + ((size_t)sp * BB * HH + bh) * SS;

    const int nT  = qt + 1;
    const int mid = (nT + 1) >> 1;
    const int lo  = sp ? mid : 0;
    const int hi  = sp ? nT  : mid;

    const int query = q0 + w * 16 + l16;

    if (lo >= hi) {   // empty split: write identity partials
        if (quad == 0) { mp[query] = -INFINITY; lp[query] = 0.f; }
        i32x4 z4 = {0, 0, 0, 0};
#pragma unroll
        for (int p2 = 0; p2 < 2; ++p2) {
            int c = p2 * 64 + lane;
            int row = c >> 3, dc = c & 7;
            *(i32x4*)&op[(size_t)(q0 + w * 16 + row) * HDD + dc * 8] = z4;
        }
        return;
    }

    __shared__ unsigned short Ks[2][64][72];    // [buf][key][d]
    __shared__ unsigned short Vt[2][64][72];    // [buf][d][key]
    __shared__ unsigned short PsT[4][16][72];   // per-wave [query(l16)][key]
    unsigned short* slab = &PsT[w][0][0];       // row stride 72

    // Q B-fragment: B[k=d][n=query(l16)]
    const bf16x8 qb0 = *(const bf16x8*)&qp[(size_t)query * HDD + quad * 8];
    const bf16x8 qb1 = *(const bf16x8*)&qp[(size_t)query * HDD + 32 + quad * 8];

    const int pr = tid >> 3;           // 0..31 (p adds 32)
    const int po = (tid & 7) * 8;

    i32x4 kpre[2], vpre[2];
#pragma unroll
    for (int p = 0; p < 2; ++p) {      // tile lo -> regs
        int r = pr + p * 32;
        kpre[p] = *(const i32x4*)&kp[(size_t)(lo * 64 + r) * HDD + po];
        vpre[p] = *(const i32x4*)&vp[(size_t)r * SS + lo * 64 + po];
    }
#pragma unroll
    for (int p = 0; p < 2; ++p) {      // -> buf 0
        int r = pr + p * 32;
        *(i32x4*)&Ks[0][r][po] = kpre[p];
        *(i32x4*)&Vt[0][r][po] = vpre[p];
    }
    if (lo + 1 < hi) {                 // prefetch tile lo+1
#pragma unroll
        for (int p = 0; p < 2; ++p) {
            int r = pr + p * 32;
            kpre[p] = *(const i32x4*)&kp[(size_t)((lo + 1) * 64 + r) * HDD + po];
            vpre[p] = *(const i32x4*)&vp[(size_t)r * SS + (lo + 1) * 64 + po];
        }
    }

    f32x4 zero = {0.f, 0.f, 0.f, 0.f};
    f32x4 o_acc[4];
    float m_i = -INFINITY, l_i = 0.f;
#pragma unroll
    for (int i = 0; i < 4; ++i) o_acc[i] = zero;

    for (int kt = lo; kt < hi; ++kt) {
        const int cbuf = (kt - lo) & 1;
        const int k0   = kt * 64;
        __syncthreads();   // buf[cbuf] visible; prior reads of cbuf^1 done

        if (kt + 1 < hi) {             // write next tile to back buffer
#pragma unroll
            for (int p = 0; p < 2; ++p) {
                int r = pr + p * 32;
                *(i32x4*)&Ks[cbuf ^ 1][r][po] = kpre[p];
                *(i32x4*)&Vt[cbuf ^ 1][r][po] = vpre[p];
            }
        }
        if (kt + 2 < hi) {             // prefetch tile kt+2
            const int kn = (kt + 2) * 64;
#pragma unroll
            for (int p = 0; p < 2; ++p) {
                int r = pr + p * 32;
                kpre[p] = *(const i32x4*)&kp[(size_t)(kn + r) * HDD + po];
                vpre[p] = *(const i32x4*)&vp[(size_t)r * SS + kn + po];
            }
        }

        // ---- S^T = K·Q^T ----
        f32x4 s_acc[4];
#pragma unroll
        for (int t = 0; t < 4; ++t) {
            bf16x8 klo = *(const bf16x8*)&Ks[cbuf][t * 16 + l16][quad * 8];
            bf16x8 khi = *(const bf16x8*)&Ks[cbuf][t * 16 + l16][32 + quad * 8];
            s_acc[t] = mfma16(klo, qb0, zero);
            s_acc[t] = mfma16(khi, qb1, s_acc[t]);
        }

        // ---- per-lane online softmax (lane owns one query) ----
        float ps[4][4];
        float mx = -INFINITY;
#pragma unroll
        for (int t = 0; t < 4; ++t)
#pragma unroll
            for (int r = 0; r < 4; ++r) {
                const int key = k0 + t * 16 + quad * 4 + r;
                float val = s_acc[t][r] * 0.125f;
                if (kt == qt && key > query) val = -INFINITY;
                ps[t][r] = val;
                mx = fmaxf(mx, val);
            }
        mx = fmaxf(mx, __shfl_xor(mx, 16));
        mx = fmaxf(mx, __shfl_xor(mx, 32));
        const float mnew  = fmaxf(m_i, mx);
        const float alpha = __expf(m_i - mnew);
        float lsum = 0.f;
#pragma unroll
        for (int t = 0; t < 4; ++t)
#pragma unroll
            for (int r = 0; r < 4; ++r) {
                float pv = __expf(ps[t][r] - mnew);
                ps[t][r] = pv;
                lsum += pv;
            }
        lsum += __shfl_xor(lsum, 16);
        lsum += __shfl_xor(lsum, 32);
        l_i = l_i * alpha + lsum;
        m_i = mnew;
#pragma unroll
        for (int t = 0; t < 4; ++t)
#pragma unroll
            for (int r = 0; r < 4; ++r) o_acc[t][r] *= alpha;

        // ---- stage P^T (per-wave slab, wave-internal, no barrier) ----
#pragma unroll
        for (int t = 0; t < 4; ++t) {
            ushort4 pk;
            pk.x = f2b(ps[t][0]);
            pk.y = f2b(ps[t][1]);
            pk.z = f2b(ps[t][2]);
            pk.w = f2b(ps[t][3]);
            *(ushort4*)&slab[l16 * 72 + t * 16 + quad * 4] = pk;
        }
        bf16x8 pb0 = *(const bf16x8*)&slab[l16 * 72 + quad * 8];
        bf16x8 pb1 = *(const bf16x8*)&slab[l16 * 72 + 32 + quad * 8];

        // ---- O^T += V^T · P^T ----
#pragma unroll
        for (int t2 = 0; t2 < 4; ++t2) {
            bf16x8 vlo = *(const bf16x8*)&Vt[cbuf][t2 * 16 + l16][quad * 8];
            bf16x8 vhi = *(const bf16x8*)&Vt[cbuf][t2 * 16 + l16][32 + quad * 8];
            o_acc[t2] = mfma16(vlo, pb0, o_acc[t2]);
            o_acc[t2] = mfma16(vhi, pb1, o_acc[t2]);
        }
    }

    // ---- epilogue: write UNNORMALIZED partials ----
    if (quad == 0) { mp[query] = m_i; lp[query] = l_i; }
#pragma unroll
    for (int t2 = 0; t2 < 4; ++t2) {
        ushort4 pk;
        pk.x = f2b(o_acc[t2][0]);
        pk.y = f2b(o_acc[t2][1]);
        pk.z = f2b(o_acc[t2][2]);
        pk.w = f2b(o_acc[t2][3]);
        *(ushort4*)&slab[l16 * 72 + t2 * 16 + quad * 4] = pk;   // T[query][d]
    }
#pragma unroll
    for (int p2 = 0; p2 < 2; ++p2) {
        int c   = p2 * 64 + lane;
        int row = c >> 3, dc = c & 7;
        *(i32x4*)&op[(size_t)(q0 + w * 16 + row) * HDD + dc * 8] =
            *(const i32x4*)&slab[row * 72 + dc * 8];
    }
}

// ---------------------------------------------------------------------------
// Merge the two split-K partials -> ctx bf16 [b*S+q][h*64+d]
// ---------------------------------------------------------------------------
__global__ __launch_bounds__(256) void merge_kernel(
    const unsigned short* __restrict__ Opart, const float* __restrict__ Mb,
    const float* __restrict__ Lb, unsigned short* __restrict__ cb)
{
    const int qt  = blockIdx.x;
    const int bhn = blockIdx.y;                 // 0..23
    const int b   = bhn / HH, h = bhn % HH;
    const int tid = threadIdx.x;
    const int row = tid >> 2;                   // 0..63
    const int d0  = (tid & 3) * 16;
    const int q   = qt * 64 + row;

    const size_t base0 = (size_t)bhn * SS;
    const size_t base1 = ((size_t)BB * HH + bhn) * SS;

    float m0 = Mb[base0 + q], m1 = Mb[base1 + q];
    float l0 = Lb[base0 + q], l1 = Lb[base1 + q];
    float M  = fmaxf(m0, m1);
    float w0 = __expf(m0 - M), w1 = __expf(m1 - M);
    float inv = 1.0f / (w0 * l0 + w1 * l1);
    w0 *= inv; w1 *= inv;

    const unsigned short* o0 = Opart + (base0 + q) * HDD + d0;
    const unsigned short* o1 = Opart + (base1 + q) * HDD + d0;
    unsigned short res[16];
#pragma unroll
    for (int i = 0; i < 16; ++i)
        res[i] = f2b(w0 * b2f(o0[i]) + w1 * b2f(o1[i]));
    unsigned short* dst = &cb[((size_t)(b * SS + q)) * DD + h * HDD + d0];
    *(i32x4*)&dst[0] = *(const i32x4*)&res[0];
    *(i32x4*)&dst[8] = *(const i32x4*)&res[8];
}

// ---------------------------------------------------------------------------
extern "C" void kernel_launch(void* const* d_in, const int* in_sizes, int n_in,
                              void* d_out, int out_size, void* d_ws, size_t ws_size,
                              hipStream_t stream)
{
    const float* x  = (const float*)d_in[0];
    const float* wq = (const float*)d_in[1];
    const float* bq = (const float*)d_in[2];
    const float* wk = (const float*)d_in[3];
    const float* bk = (const float*)d_in[4];
    const float* wv = (const float*)d_in[5];
    const float* bv = (const float*)d_in[6];
    const float* wo = (const float*)d_in[7];
    const float* bo = (const float*)d_in[8];
    float* out = (float*)d_out;

    char* p = (char*)d_ws;
    const size_t XB = (size_t)BSR * DD * 2;          // 6.29 MB (bf16 activations)
    const size_t WB = (size_t)DD * DD * 2;           // 1.18 MB
    const size_t MLB = (size_t)2 * BB * HH * SS * 4; // m or l, both splits
    unsigned short* xb  = (unsigned short*)p;            p += XB;
    unsigned short* wqT = (unsigned short*)p;            p += WB;
    unsigned short* wkT = (unsigned short*)p;            p += WB;
    unsigned short* wvT = (unsigned short*)p;            p += WB;
    unsigned short* woT = (unsigned short*)p;            p += WB;
    unsigned short* Qg  = (unsigned short*)p;            p += XB;
    unsigned short* Kg  = (unsigned short*)p;            p += XB;
    unsigned short* Vg  = (unsigned short*)p;            p += XB;
    unsigned short* cb  = (unsigned short*)p;            p += XB;
    unsigned short* Opart = (unsigned short*)p;          p += 2 * XB;
    float* Mb = (float*)p;                               p += MLB;
    float* Lb = (float*)p;                               p += MLB;

    conv_x_kernel<<<BSR * DD / (256 * 8), 256, 0, stream>>>(x, xb);
    conv_wT_kernel<<<dim3(DD / 64, DD / 64, 4), 256, 0, stream>>>(
        wq, wk, wv, wo, wqT, wkT, wvT, woT);
    qkv_gemm_kernel<<<dim3(BSR / 64, DD / 128, 3), 256, 0, stream>>>(
        xb, wqT, wkT, wvT, bq, bk, bv, Qg, Kg, Vg);
    attn_mfma_kernel<<<dim3(NQT * 2, HH, BB), 256, 0, stream>>>(
        Qg, Kg, Vg, Opart, Mb, Lb);
    merge_kernel<<<dim3(NQT, BB * HH), 256, 0, stream>>>(Opart, Mb, Lb, cb);
    out_gemm_kernel<<<dim3(BSR / 64, DD / 128), 256, 0, stream>>>(cb, woT, bo, out);
}